// Round 8
// baseline (222.563 us; speedup 1.0000x reference)
//
#include <hip/hip_runtime.h>

#define NN 64
// ---- ws layout (uint4 units) ----
#define B_PER_MAT (8 * 14 * 64) // 7168
#define B_OFF 0
#define PART_OFF_F (128 * B_PER_MAT * 4) // float offset (after 14.7 MB B frags)

typedef __attribute__((ext_vector_type(8))) short short8;
typedef __attribute__((ext_vector_type(4))) float f32x4;

__device__ __forceinline__ float waveSum(float v) {
#pragma unroll
  for (int m = 1; m < 64; m <<= 1) v += __shfl_xor(v, m, 64);
  return v;
}

// min across each 16-lane DPP row via quad_perm/row_ror (VALU, no LDS)
__device__ __forceinline__ float rowMin16(float v) {
  int x = __builtin_bit_cast(int, v);
  v = fminf(v, __builtin_bit_cast(float, __builtin_amdgcn_update_dpp(x, x, 0xB1, 0xF, 0xF, true)));
  x = __builtin_bit_cast(int, v);
  v = fminf(v, __builtin_bit_cast(float, __builtin_amdgcn_update_dpp(x, x, 0x4E, 0xF, 0xF, true)));
  x = __builtin_bit_cast(int, v);
  v = fminf(v, __builtin_bit_cast(float, __builtin_amdgcn_update_dpp(x, x, 0x124, 0xF, 0xF, true)));
  x = __builtin_bit_cast(int, v);
  v = fminf(v, __builtin_bit_cast(float, __builtin_amdgcn_update_dpp(x, x, 0x128, 0xF, 0xF, true)));
  return v;
}

// RNE float -> bf16
__device__ __forceinline__ unsigned short f2bf(float f) {
  unsigned u = __builtin_bit_cast(unsigned, f);
  u += 0x7FFFu + ((u >> 16) & 1u);
  return (unsigned short)(u >> 16);
}
__device__ __forceinline__ unsigned packbf(float a, float b) {
  return (unsigned)f2bf(a) | ((unsigned)f2bf(b) << 16);
}

// Register-transpose convert of gl_pr only: one block per (matrix, kc8).
// frag layout per mat: [kc8(8)][tile(14)][lane=quad*16+li][8 bf16]
// element e of frag = src[(kc8*32 + quad*8 + e)*196 + tile*16 + li]
__global__ void __launch_bounds__(256) convert_b_kernel(
    const float* __restrict__ gl_pr, uint4* __restrict__ ws) {
  const int b = blockIdx.x;
  const int m = b >> 3, kc8 = b & 7;
  const float* src = gl_pr + (size_t)m * 256 * 196 + (size_t)kc8 * 32 * 196;
  uint4* dst = ws + B_OFF + (size_t)m * B_PER_MAT + kc8 * 14 * 64;

  const int quad = threadIdx.x >> 6, colq = threadIdx.x & 63;
  if (colq >= 56) return;
  const int col0 = colq * 4;
  uint4 u0, u1, u2, u3;
  if (col0 < 196) {
    const float* p = src + (size_t)(quad * 8) * 196 + col0;
    float4 g[8];
#pragma unroll
    for (int e = 0; e < 8; ++e) g[e] = *(const float4*)(p + (size_t)e * 196);
    u0.x = packbf(g[0].x, g[1].x); u0.y = packbf(g[2].x, g[3].x);
    u0.z = packbf(g[4].x, g[5].x); u0.w = packbf(g[6].x, g[7].x);
    u1.x = packbf(g[0].y, g[1].y); u1.y = packbf(g[2].y, g[3].y);
    u1.z = packbf(g[4].y, g[5].y); u1.w = packbf(g[6].y, g[7].y);
    u2.x = packbf(g[0].z, g[1].z); u2.y = packbf(g[2].z, g[3].z);
    u2.z = packbf(g[4].z, g[5].z); u2.w = packbf(g[6].z, g[7].z);
    u3.x = packbf(g[0].w, g[1].w); u3.y = packbf(g[2].w, g[3].w);
    u3.z = packbf(g[4].w, g[5].w); u3.w = packbf(g[6].w, g[7].w);
  } else {
    u0 = u1 = u2 = u3 = make_uint4(0, 0, 0, 0);
  }
  const int tile = colq >> 2, li0 = col0 & 15;
  uint4* d = dst + (size_t)tile * 64 + quad * 16 + li0;
  d[0] = u0; d[1] = u1; d[2] = u2; d[3] = u3;
}

// gather A frags for 64-ch chunk C8 into two uint4 regs (guarded by `active`)
#define GATHER_A(C8, A0, A1)                                                 \
  if (active) {                                                              \
    const float* p0 = agp + (size_t)((C8) * 64) * Q;                         \
    const float* p1 = p0 + (size_t)32 * Q;                                   \
    float v0[8], v1[8];                                                      \
    _Pragma("unroll") for (int e = 0; e < 8; ++e) {                          \
      v0[e] = rvalid ? p0[(size_t)e * Q] : 0.0f;                             \
      v1[e] = rvalid ? p1[(size_t)e * Q] : 0.0f;                             \
    }                                                                        \
    A0.x = packbf(v0[0], v0[1]); A0.y = packbf(v0[2], v0[3]);                \
    A0.z = packbf(v0[4], v0[5]); A0.w = packbf(v0[6], v0[7]);                \
    A1.x = packbf(v1[0], v1[1]); A1.y = packbf(v1[2], v1[3]);                \
    A1.z = packbf(v1[4], v1[5]); A1.w = packbf(v1[6], v1[7]);                \
  }

// issue async global->LDS for B chunk C8 (wave-uniform base + lane*16)
#define ISSUE_B(C8)                                                          \
  {                                                                          \
    const uint4* bs = bbase + (size_t)(C8) * (2 * 14 * 64);                  \
    _Pragma("unroll") for (int it = 0; it < 7; ++it) {                       \
      int idx = it * 256 + (w << 6);                                         \
      __builtin_amdgcn_global_load_lds(                                      \
          (const __attribute__((address_space(1))) void*)(bs + idx + lane),  \
          (__attribute__((address_space(3))) void*)((uint4*)bbuf + idx),     \
          16, 0, 0);                                                         \
    }                                                                        \
  }

#define MFMA_HALF(KC, AREG)                                                  \
  if (active) {                                                              \
    _Pragma("unroll") for (int t = 0; t < 14; ++t) {                         \
      short8 bf = __builtin_bit_cast(short8, bbuf[KC][t][lane]);             \
      acc[t] = __builtin_amdgcn_mfma_f32_16x16x32_bf16(                      \
          __builtin_bit_cast(short8, AREG), bf, acc[t], 0, 0, 0);            \
    }                                                                        \
  }

__global__ void __launch_bounds__(256, 5) triplet_main(
    const float* __restrict__ gl_sa, const float* __restrict__ lo_sa,
    const uint4* __restrict__ ws, const float* __restrict__ coords,
    float* __restrict__ partials) {
  __shared__ uint4 bbuf[2][14][64]; // 28672 B, B frags for one 64-ch chunk
  __shared__ float red[3][4];
  const int tid = threadIdx.x;
  const int lane = tid & 63;
  const int li = lane & 15;
  const int quad = lane >> 4;
  const int w = tid >> 6;

  // block order: 16 consecutive blocks share B(j,n)
  int b = blockIdx.x;
  int jn = b >> 4, u = b & 15;
  int j = jn >> 6, n = jn & 63;
  const uint4* bbase = ws + B_OFF + (size_t)(j * NN + n) * B_PER_MAT;
  const float *cqp, *ckp = coords + (j * NN + n) * 4;
  const float* asrc;
  int Q, Wq, ntA, rowbase;
  if (u < 4) { // gl term: q = gl_sa[1-j], k = gl_pr[j]
    rowbase = u * 64;
    Q = 196; Wq = 14; ntA = 13;
    asrc = gl_sa + (size_t)((1 - j) * NN + n) * 256 * 196;
    cqp = coords + ((1 - j) * NN + n) * 4;
  } else { // lo term i
    int v = u - 4, i = v >> 1, g = v & 1;
    rowbase = g * 64;
    Q = 100; Wq = 10; ntA = 7;
    asrc = lo_sa + (size_t)(i * NN + n) * 256 * 100;
    cqp = coords + ((2 + i) * NN + n) * 4;
  }
  const int rt = (rowbase >> 4) + w; // this wave's A row-tile
  const bool active = rt < ntA;
  const int arow = rt * 16 + li;
  const bool rvalid = active && (arow < Q);
  const float* agp = asrc + (size_t)(quad * 8) * Q + (rvalid ? arow : 0);

  f32x4 acc[14];
#pragma unroll
  for (int t = 0; t < 14; ++t) acc[t] = 0.0f;

  // software-pipelined K-loop: A[c+1] gathered between MFMA halves of chunk c
  uint4 a0A, a1A, a0B, a1B;
  ISSUE_B(0);
  GATHER_A(0, a0A, a1A);
  __syncthreads(); // drains B DMA 0 (+ A0 loads)

  MFMA_HALF(0, a0A);
  GATHER_A(1, a0B, a1B);
  MFMA_HALF(1, a1A);
  __syncthreads(); // all waves done reading bbuf chunk 0
  ISSUE_B(1);
  __syncthreads(); // drains B DMA 1 (A1 already packed)

  MFMA_HALF(0, a0B);
  GATHER_A(2, a0A, a1A);
  MFMA_HALF(1, a1B);
  __syncthreads();
  ISSUE_B(2);
  __syncthreads();

  MFMA_HALF(0, a0A);
  GATHER_A(3, a0B, a1B);
  MFMA_HALF(1, a1A);
  __syncthreads();
  ISSUE_B(3);
  __syncthreads();

  MFMA_HALF(0, a0B);
  MFMA_HALF(1, a1B);

  // ---- geometry ----
  const float qx0 = cqp[0], qy0 = cqp[1];
  const float bwq = (cqp[2] - qx0) / (float)Wq;
  const float bhq = (cqp[3] - qy0) / (float)Wq;
  const float kx0 = ckp[0], ky0 = ckp[1];
  const float bwk = (ckp[2] - kx0) / 14.0f;
  const float bhk = (ckp[3] - ky0) / 14.0f;
  const float qd = sqrtf(bwq * bwq + bhq * bhq);
  const float kd = sqrtf(bwk * bwk + bhk * bhk);
  const float md = fmaxf(qd, kd);
  const float thr2 = 0.49f * md * md; // dist<0.7 <=> d2 < (0.7*md)^2
  const float INFV = __builtin_inff();

  float ckx[14], cky[14];
  unsigned kvalid = 0;
#pragma unroll
  for (int t = 0; t < 14; ++t) {
    int col = t * 16 + li;
    if (col < 196) kvalid |= (1u << t);
    int xk = col % 14, yk = col / 14; // compile-time 14: magic mul
    ckx[t] = ((float)xk + 0.5f) * bwk + kx0;
    cky[t] = ((float)yk + 0.5f) * bhk + ky0;
  }

  // r/Wq via magic multiply (r < 256): 4682 for 14, 6554 for 10
  const unsigned Mdiv = (Wq == 14) ? 4682u : 6554u;
  unsigned r0u = (unsigned)(rowbase + w * 16 + quad * 4);
  unsigned yq = (r0u * Mdiv) >> 16;
  unsigned xq = r0u - yq * (unsigned)Wq;

  // ---- fused epilogue on MFMA C layout: quad owns rows quad*4+rg ----
  float psum = 0.f, pcnt = 0.f, nsum = 0.f;
#pragma unroll
  for (int rg = 0; rg < 4; ++rg) {
    int r = rowbase + w * 16 + quad * 4 + rg; // quad-uniform
    if (r < Q) {
      float cqx = ((float)xq + 0.5f) * bwq + qx0;
      float cqy = ((float)yq + 0.5f) * bhq + qy0;
      // per-lane sorted smallest-5 + min-of-rest, via insertion
      float s0v = INFV, s1v = INFV, s2v = INFV, s3v = INFV, s4v = INFV,
            rest = INFV;
#pragma unroll
      for (int t = 0; t < 14; ++t) {
        float v = -2.0f * acc[t][rg];
        float dx = cqx - ckx[t], dy = cqy - cky[t];
        float d2 = dx * dx + dy * dy;
        bool kv = (kvalid >> t) & 1;
        bool pos = kv && (d2 < thr2);
        psum += pos ? v : 0.0f;
        pcnt += pos ? 1.0f : 0.0f;
        float a = (kv && !pos) ? v : INFV;
        float mn;
        mn = fminf(a, s0v); a = fmaxf(a, s0v); s0v = mn;
        mn = fminf(a, s1v); a = fmaxf(a, s1v); s1v = mn;
        mn = fminf(a, s2v); a = fmaxf(a, s2v); s2v = mn;
        mn = fminf(a, s3v); a = fmaxf(a, s3v); s3v = mn;
        mn = fminf(a, s4v); a = fmaxf(a, s4v); s4v = mn;
        rest = fminf(rest, a);
      }
      float mm = rowMin16(s0v);
      float first = mm, total = mm;
      {
        unsigned long long bal = __ballot(s0v == mm);
        unsigned qb = (unsigned)(bal >> (quad << 4)) & 0xFFFFu;
        if (li == __ffs(qb) - 1) {
          s0v = s1v; s1v = s2v; s2v = s3v; s3v = s4v; s4v = rest; rest = INFV;
        }
      }
#pragma unroll 1
      for (int s = 1; s < 10; ++s) {
        mm = rowMin16(s0v);
        total += mm;
        unsigned long long bal = __ballot(s0v == mm);
        unsigned qb = (unsigned)(bal >> (quad << 4)) & 0xFFFFu;
        if (li == __ffs(qb) - 1) {
          s0v = s1v; s1v = s2v; s2v = s3v; s3v = s4v; s4v = rest; rest = INFV;
        }
      }
      if (li == 0) nsum += (total - first) * (1.0f / 9.0f);
    }
    xq++;
    if (xq == (unsigned)Wq) { xq = 0; yq++; }
  }

  psum = waveSum(psum);
  pcnt = waveSum(pcnt);
  nsum = waveSum(nsum);
  if (lane == 0) {
    red[0][w] = psum;
    red[1][w] = pcnt;
    red[2][w] = nsum;
  }
  __syncthreads();
  if (tid == 0) {
    float* pb = partials + (size_t)blockIdx.x * 3;
    pb[0] = red[0][0] + red[0][1] + red[0][2] + red[0][3];
    pb[1] = red[1][0] + red[1][1] + red[1][2] + red[1][3];
    pb[2] = red[2][0] + red[2][1] + red[2][2] + red[2][3];
  }
}

__global__ void __launch_bounds__(256) finalize_kernel(
    const float* __restrict__ partials, float* __restrict__ out) {
  int tid = threadIdx.x;
  float sum = 0.f;
  for (int e = tid; e < 14 * NN; e += 256) {
    float P = 0.f, C = 0.f, Ns = 0.f, Qf;
    if (e < 128) { // gl term t: blocks ((t*64+n)*16 + 0..3)
      int t = e >> 6, n = e & 63;
      Qf = 196.0f;
      int base = ((t * 64 + n) * 16) * 3;
#pragma unroll
      for (int g = 0; g < 4; ++g) {
        P += partials[base + 3 * g];
        C += partials[base + 3 * g + 1];
        Ns += partials[base + 3 * g + 2];
      }
    } else { // lo term (j,i): blocks ((j*64+n)*16 + 4 + 2i + {0,1})
      int s = e - 128;
      int idx = s >> 6, n = s & 63;
      int j = idx / 6, i = idx - 6 * j;
      Qf = 100.0f;
      int base = ((j * 64 + n) * 16 + 4 + 2 * i) * 3;
#pragma unroll
      for (int g = 0; g < 2; ++g) {
        P += partials[base + 3 * g];
        C += partials[base + 3 * g + 1];
        Ns += partials[base + 3 * g + 2];
      }
    }
    float positives = P / (C + 1e-6f);
    float negatives = Ns / Qf;
    sum += fmaxf(0.0f, 100.0f - (negatives - 2.0f * positives));
  }
  sum = waveSum(sum);
  __shared__ float ssum[4];
  if ((tid & 63) == 0) ssum[tid >> 6] = sum;
  __syncthreads();
  if (tid == 0) out[0] = (ssum[0] + ssum[1] + ssum[2] + ssum[3]) * (1.0f / (14 * NN));
}

extern "C" void kernel_launch(void* const* d_in, const int* in_sizes, int n_in,
                              void* d_out, int out_size, void* d_ws, size_t ws_size,
                              hipStream_t stream) {
  const float* gl_sa = (const float*)d_in[0];
  const float* lo_sa = (const float*)d_in[1];
  const float* gl_pr = (const float*)d_in[2];
  const float* coords = (const float*)d_in[3];
  uint4* frags = (uint4*)d_ws;
  float* partials = (float*)d_ws + PART_OFF_F;
  float* out = (float*)d_out;

  convert_b_kernel<<<1024, 256, 0, stream>>>(gl_pr, frags);
  triplet_main<<<2048, 256, 0, stream>>>(gl_sa, lo_sa, frags, coords, partials);
  finalize_kernel<<<1, 256, 0, stream>>>(partials, out);
}

// Round 9
// 166.330 us; speedup vs baseline: 1.3381x; 1.3381x over previous
//
#include <hip/hip_runtime.h>

#define NN 64
// ---- ws layout (uint4 units) ----
#define B_PER_MAT (8 * 14 * 64) // 7168
#define B_OFF 0
#define PART_OFF_F (128 * B_PER_MAT * 4) // float offset (after 14.7 MB B frags)

typedef __attribute__((ext_vector_type(8))) short short8;
typedef __attribute__((ext_vector_type(4))) float f32x4;

__device__ __forceinline__ float waveSum(float v) {
#pragma unroll
  for (int m = 1; m < 64; m <<= 1) v += __shfl_xor(v, m, 64);
  return v;
}

// min across each 16-lane DPP row via quad_perm/row_ror (VALU, no LDS)
__device__ __forceinline__ float rowMin16(float v) {
  int x = __builtin_bit_cast(int, v);
  v = fminf(v, __builtin_bit_cast(float, __builtin_amdgcn_update_dpp(x, x, 0xB1, 0xF, 0xF, true)));
  x = __builtin_bit_cast(int, v);
  v = fminf(v, __builtin_bit_cast(float, __builtin_amdgcn_update_dpp(x, x, 0x4E, 0xF, 0xF, true)));
  x = __builtin_bit_cast(int, v);
  v = fminf(v, __builtin_bit_cast(float, __builtin_amdgcn_update_dpp(x, x, 0x124, 0xF, 0xF, true)));
  x = __builtin_bit_cast(int, v);
  v = fminf(v, __builtin_bit_cast(float, __builtin_amdgcn_update_dpp(x, x, 0x128, 0xF, 0xF, true)));
  return v;
}

// RNE float -> bf16
__device__ __forceinline__ unsigned short f2bf(float f) {
  unsigned u = __builtin_bit_cast(unsigned, f);
  u += 0x7FFFu + ((u >> 16) & 1u);
  return (unsigned short)(u >> 16);
}
__device__ __forceinline__ unsigned packbf(float a, float b) {
  return (unsigned)f2bf(a) | ((unsigned)f2bf(b) << 16);
}

// Register-transpose convert of gl_pr only: one block per (matrix, kc8).
// frag layout per mat: [kc8(8)][tile(14)][lane=quad*16+li][8 bf16]
// element e of frag = src[(kc8*32 + quad*8 + e)*196 + tile*16 + li]
__global__ void __launch_bounds__(256) convert_b_kernel(
    const float* __restrict__ gl_pr, uint4* __restrict__ ws) {
  const int b = blockIdx.x;
  const int m = b >> 3, kc8 = b & 7;
  const float* src = gl_pr + (size_t)m * 256 * 196 + (size_t)kc8 * 32 * 196;
  uint4* dst = ws + B_OFF + (size_t)m * B_PER_MAT + kc8 * 14 * 64;

  const int quad = threadIdx.x >> 6, colq = threadIdx.x & 63;
  if (colq >= 56) return;
  const int col0 = colq * 4;
  uint4 u0, u1, u2, u3;
  if (col0 < 196) {
    const float* p = src + (size_t)(quad * 8) * 196 + col0;
    float4 g[8];
#pragma unroll
    for (int e = 0; e < 8; ++e) g[e] = *(const float4*)(p + (size_t)e * 196);
    u0.x = packbf(g[0].x, g[1].x); u0.y = packbf(g[2].x, g[3].x);
    u0.z = packbf(g[4].x, g[5].x); u0.w = packbf(g[6].x, g[7].x);
    u1.x = packbf(g[0].y, g[1].y); u1.y = packbf(g[2].y, g[3].y);
    u1.z = packbf(g[4].y, g[5].y); u1.w = packbf(g[6].y, g[7].y);
    u2.x = packbf(g[0].z, g[1].z); u2.y = packbf(g[2].z, g[3].z);
    u2.z = packbf(g[4].z, g[5].z); u2.w = packbf(g[6].z, g[7].z);
    u3.x = packbf(g[0].w, g[1].w); u3.y = packbf(g[2].w, g[3].w);
    u3.z = packbf(g[4].w, g[5].w); u3.w = packbf(g[6].w, g[7].w);
  } else {
    u0 = u1 = u2 = u3 = make_uint4(0, 0, 0, 0);
  }
  const int tile = colq >> 2, li0 = col0 & 15;
  uint4* d = dst + (size_t)tile * 64 + quad * 16 + li0;
  d[0] = u0; d[1] = u1; d[2] = u2; d[3] = u3;
}

// gather A frags for 64-ch chunk C8 into two uint4 regs (guarded by `active`)
#define GATHER_A(C8, A0, A1)                                                 \
  if (active) {                                                              \
    const float* p0 = agp + (size_t)((C8) * 64) * Q;                         \
    const float* p1 = p0 + (size_t)32 * Q;                                   \
    float v0[8], v1[8];                                                      \
    _Pragma("unroll") for (int e = 0; e < 8; ++e) {                          \
      v0[e] = rvalid ? p0[(size_t)e * Q] : 0.0f;                             \
      v1[e] = rvalid ? p1[(size_t)e * Q] : 0.0f;                             \
    }                                                                        \
    A0.x = packbf(v0[0], v0[1]); A0.y = packbf(v0[2], v0[3]);                \
    A0.z = packbf(v0[4], v0[5]); A0.w = packbf(v0[6], v0[7]);                \
    A1.x = packbf(v1[0], v1[1]); A1.y = packbf(v1[2], v1[3]);                \
    A1.z = packbf(v1[4], v1[5]); A1.w = packbf(v1[6], v1[7]);                \
  }

// issue async global->LDS for B chunk C8 (wave-uniform base + lane*16)
#define ISSUE_B(C8)                                                          \
  {                                                                          \
    const uint4* bs = bbase + (size_t)(C8) * (2 * 14 * 64);                  \
    _Pragma("unroll") for (int it = 0; it < 7; ++it) {                       \
      int idx = it * 256 + (w << 6);                                         \
      __builtin_amdgcn_global_load_lds(                                      \
          (const __attribute__((address_space(1))) void*)(bs + idx + lane),  \
          (__attribute__((address_space(3))) void*)((uint4*)bbuf + idx),     \
          16, 0, 0);                                                         \
    }                                                                        \
  }

#define MFMA_HALF(KC, AREG)                                                  \
  if (active) {                                                              \
    _Pragma("unroll") for (int t = 0; t < 14; ++t) {                         \
      short8 bf = __builtin_bit_cast(short8, bbuf[KC][t][lane]);             \
      acc[t] = __builtin_amdgcn_mfma_f32_16x16x32_bf16(                      \
          __builtin_bit_cast(short8, AREG), bf, acc[t], 0, 0, 0);            \
    }                                                                        \
  }

__global__ void __launch_bounds__(256, 4) triplet_main(
    const float* __restrict__ gl_sa, const float* __restrict__ lo_sa,
    const uint4* __restrict__ ws, const float* __restrict__ coords,
    float* __restrict__ partials) {
  __shared__ uint4 bbuf[2][14][64]; // 28672 B, B frags for one 64-ch chunk
  __shared__ float red[3][4];
  const int tid = threadIdx.x;
  const int lane = tid & 63;
  const int li = lane & 15;
  const int quad = lane >> 4;
  const int w = tid >> 6;

  // block order: 16 consecutive blocks share B(j,n)
  int b = blockIdx.x;
  int jn = b >> 4, u = b & 15;
  int j = jn >> 6, n = jn & 63;
  const uint4* bbase = ws + B_OFF + (size_t)(j * NN + n) * B_PER_MAT;
  const float *cqp, *ckp = coords + (j * NN + n) * 4;
  const float* asrc;
  int Q, Wq, ntA, rowbase;
  if (u < 4) { // gl term: q = gl_sa[1-j], k = gl_pr[j]
    rowbase = u * 64;
    Q = 196; Wq = 14; ntA = 13;
    asrc = gl_sa + (size_t)((1 - j) * NN + n) * 256 * 196;
    cqp = coords + ((1 - j) * NN + n) * 4;
  } else { // lo term i
    int v = u - 4, i = v >> 1, g = v & 1;
    rowbase = g * 64;
    Q = 100; Wq = 10; ntA = 7;
    asrc = lo_sa + (size_t)(i * NN + n) * 256 * 100;
    cqp = coords + ((2 + i) * NN + n) * 4;
  }
  const int rt = (rowbase >> 4) + w; // this wave's A row-tile
  const bool active = rt < ntA;
  const int arow = rt * 16 + li;
  const bool rvalid = active && (arow < Q);
  const float* agp = asrc + (size_t)(quad * 8) * Q + (rvalid ? arow : 0);

  f32x4 acc[14];
#pragma unroll
  for (int t = 0; t < 14; ++t) acc[t] = 0.0f;

  // software-pipelined K-loop: A[c+1] gathered between MFMA halves of chunk c
  uint4 a0A, a1A, a0B, a1B;
  ISSUE_B(0);
  GATHER_A(0, a0A, a1A);
  __syncthreads(); // drains B DMA 0 (+ A0 loads)

  MFMA_HALF(0, a0A);
  GATHER_A(1, a0B, a1B);
  MFMA_HALF(1, a1A);
  __syncthreads(); // all waves done reading bbuf chunk 0
  ISSUE_B(1);
  __syncthreads(); // drains B DMA 1 (A1 already packed)

  MFMA_HALF(0, a0B);
  GATHER_A(2, a0A, a1A);
  MFMA_HALF(1, a1B);
  __syncthreads();
  ISSUE_B(2);
  __syncthreads();

  MFMA_HALF(0, a0A);
  GATHER_A(3, a0B, a1B);
  MFMA_HALF(1, a1A);
  __syncthreads();
  ISSUE_B(3);
  __syncthreads();

  MFMA_HALF(0, a0B);
  MFMA_HALF(1, a1B);

  // ---- geometry ----
  const float qx0 = cqp[0], qy0 = cqp[1];
  const float bwq = (cqp[2] - qx0) / (float)Wq;
  const float bhq = (cqp[3] - qy0) / (float)Wq;
  const float kx0 = ckp[0], ky0 = ckp[1];
  const float bwk = (ckp[2] - kx0) / 14.0f;
  const float bhk = (ckp[3] - ky0) / 14.0f;
  const float qd = sqrtf(bwq * bwq + bhq * bhq);
  const float kd = sqrtf(bwk * bwk + bhk * bhk);
  const float md = fmaxf(qd, kd);
  const float thr2 = 0.49f * md * md; // dist<0.7 <=> d2 < (0.7*md)^2
  const float INFV = __builtin_inff();

  float ckx[14], cky[14];
  unsigned kvalid = 0;
#pragma unroll
  for (int t = 0; t < 14; ++t) {
    int col = t * 16 + li;
    if (col < 196) kvalid |= (1u << t);
    int xk = col % 14, yk = col / 14; // compile-time 14: magic mul
    ckx[t] = ((float)xk + 0.5f) * bwk + kx0;
    cky[t] = ((float)yk + 0.5f) * bhk + ky0;
  }

  // r/Wq via magic multiply (r < 256): 4682 for 14, 6554 for 10
  const unsigned Mdiv = (Wq == 14) ? 4682u : 6554u;
  unsigned r0u = (unsigned)(rowbase + w * 16 + quad * 4);
  unsigned yq = (r0u * Mdiv) >> 16;
  unsigned xq = r0u - yq * (unsigned)Wq;

  // ---- fused epilogue on MFMA C layout: quad owns rows quad*4+rg ----
  float psum = 0.f, pcnt = 0.f, nsum = 0.f;
#pragma unroll
  for (int rg = 0; rg < 4; ++rg) {
    int r = rowbase + w * 16 + quad * 4 + rg; // quad-uniform
    if (r < Q) {
      float cqx = ((float)xq + 0.5f) * bwq + qx0;
      float cqy = ((float)yq + 0.5f) * bhq + qy0;
      // per-lane sorted smallest-5 + min-of-rest, via insertion
      float s0v = INFV, s1v = INFV, s2v = INFV, s3v = INFV, s4v = INFV,
            rest = INFV;
#pragma unroll
      for (int t = 0; t < 14; ++t) {
        float v = -2.0f * acc[t][rg];
        float dx = cqx - ckx[t], dy = cqy - cky[t];
        float d2 = dx * dx + dy * dy;
        bool kv = (kvalid >> t) & 1;
        bool pos = kv && (d2 < thr2);
        psum += pos ? v : 0.0f;
        pcnt += pos ? 1.0f : 0.0f;
        float a = (kv && !pos) ? v : INFV;
        float mn;
        mn = fminf(a, s0v); a = fmaxf(a, s0v); s0v = mn;
        mn = fminf(a, s1v); a = fmaxf(a, s1v); s1v = mn;
        mn = fminf(a, s2v); a = fmaxf(a, s2v); s2v = mn;
        mn = fminf(a, s3v); a = fmaxf(a, s3v); s3v = mn;
        mn = fminf(a, s4v); a = fmaxf(a, s4v); s4v = mn;
        rest = fminf(rest, a);
      }
      float mm = rowMin16(s0v);
      float first = mm, total = mm;
      {
        unsigned long long bal = __ballot(s0v == mm);
        unsigned qb = (unsigned)(bal >> (quad << 4)) & 0xFFFFu;
        if (li == __ffs(qb) - 1) {
          s0v = s1v; s1v = s2v; s2v = s3v; s3v = s4v; s4v = rest; rest = INFV;
        }
      }
#pragma unroll 1
      for (int s = 1; s < 10; ++s) {
        mm = rowMin16(s0v);
        total += mm;
        unsigned long long bal = __ballot(s0v == mm);
        unsigned qb = (unsigned)(bal >> (quad << 4)) & 0xFFFFu;
        if (li == __ffs(qb) - 1) {
          s0v = s1v; s1v = s2v; s2v = s3v; s3v = s4v; s4v = rest; rest = INFV;
        }
      }
      if (li == 0) nsum += (total - first) * (1.0f / 9.0f);
    }
    xq++;
    if (xq == (unsigned)Wq) { xq = 0; yq++; }
  }

  psum = waveSum(psum);
  pcnt = waveSum(pcnt);
  nsum = waveSum(nsum);
  if (lane == 0) {
    red[0][w] = psum;
    red[1][w] = pcnt;
    red[2][w] = nsum;
  }
  __syncthreads();
  if (tid == 0) {
    float* pb = partials + (size_t)blockIdx.x * 3;
    pb[0] = red[0][0] + red[0][1] + red[0][2] + red[0][3];
    pb[1] = red[1][0] + red[1][1] + red[1][2] + red[1][3];
    pb[2] = red[2][0] + red[2][1] + red[2][2] + red[2][3];
  }
}

__global__ void __launch_bounds__(256) finalize_kernel(
    const float* __restrict__ partials, float* __restrict__ out) {
  int tid = threadIdx.x;
  float sum = 0.f;
  for (int e = tid; e < 14 * NN; e += 256) {
    float P = 0.f, C = 0.f, Ns = 0.f, Qf;
    if (e < 128) { // gl term t: blocks ((t*64+n)*16 + 0..3)
      int t = e >> 6, n = e & 63;
      Qf = 196.0f;
      int base = ((t * 64 + n) * 16) * 3;
#pragma unroll
      for (int g = 0; g < 4; ++g) {
        P += partials[base + 3 * g];
        C += partials[base + 3 * g + 1];
        Ns += partials[base + 3 * g + 2];
      }
    } else { // lo term (j,i): blocks ((j*64+n)*16 + 4 + 2i + {0,1})
      int s = e - 128;
      int idx = s >> 6, n = s & 63;
      int j = idx / 6, i = idx - 6 * j;
      Qf = 100.0f;
      int base = ((j * 64 + n) * 16 + 4 + 2 * i) * 3;
#pragma unroll
      for (int g = 0; g < 2; ++g) {
        P += partials[base + 3 * g];
        C += partials[base + 3 * g + 1];
        Ns += partials[base + 3 * g + 2];
      }
    }
    float positives = P / (C + 1e-6f);
    float negatives = Ns / Qf;
    sum += fmaxf(0.0f, 100.0f - (negatives - 2.0f * positives));
  }
  sum = waveSum(sum);
  __shared__ float ssum[4];
  if ((tid & 63) == 0) ssum[tid >> 6] = sum;
  __syncthreads();
  if (tid == 0) out[0] = (ssum[0] + ssum[1] + ssum[2] + ssum[3]) * (1.0f / (14 * NN));
}

extern "C" void kernel_launch(void* const* d_in, const int* in_sizes, int n_in,
                              void* d_out, int out_size, void* d_ws, size_t ws_size,
                              hipStream_t stream) {
  const float* gl_sa = (const float*)d_in[0];
  const float* lo_sa = (const float*)d_in[1];
  const float* gl_pr = (const float*)d_in[2];
  const float* coords = (const float*)d_in[3];
  uint4* frags = (uint4*)d_ws;
  float* partials = (float*)d_ws + PART_OFF_F;
  float* out = (float*)d_out;

  convert_b_kernel<<<1024, 256, 0, stream>>>(gl_pr, frags);
  triplet_main<<<2048, 256, 0, stream>>>(gl_sa, lo_sa, frags, coords, partials);
  finalize_kernel<<<1, 256, 0, stream>>>(partials, out);
}